// Round 4
// baseline (122.716 us; speedup 1.0000x reference)
//
#include <hip/hip_runtime.h>
#include <math.h>

// (B,P,V,F,H) = (32,512,32,16,64). Round 8: amortize the WF stream.
// Evidence: v5 (4 w/SIMD, no spill), v6 (~5.6 w/SIMD, 70 MB spill), v7
// (6 w/SIMD) all ~49 us/dispatch -> runtime invariant to occupancy AND
// spill => per-wave fixed cost on a shared pipe. Arithmetic: every wave
// streams the same 36 KB of W-frags (36 x dwordx4 = 1 KB/instr) + ~6 KB
// X/M/bias = ~43 KB through L1/TA x 16384 waves ~ 2.75 MB/CU ~ 20+ us of
// VMEM pipe occupancy, alongside a ~23 us VALU floor (0.47 x 49.5).
// Fix: TWO bp per wave -> each wf fragment load feeds 4 MFMAs (both bp),
// halving per-bp VMEM traffic; MFMA/VALU work per bp unchanged.
// acc doubles to 64 f32 -> peak ~140 regs: __launch_bounds__(256,3)
// (cap 170, guaranteed spill-free; round-6 lesson: never under-cap).
// Occupancy-invariance observed above makes 3 waves/SIMD safe; each wave
// now carries 2x independent ILP. LDS 37.9 KB x 3 blocks = 114 KB OK.
// Keeps: single LDS buffer per (wave,bp), addm[]=0/-inf pool masking,
// v_cvt_pk_bf16_f32 packing, no per-element out-mask (output = pools only).
// MFMA 16x16x32 bf16: A[m=lane&15][k=quad*8+j], B[k=quad*8+j][n=lane&15],
//                     D[row=quad*4+reg][col=lane&15]  (verified rounds 2-4).
namespace {
constexpr int kXS = 72;
constexpr float kSlope = 0.01f;

typedef short bf16x8 __attribute__((ext_vector_type(8)));
typedef float f32x4  __attribute__((ext_vector_type(4)));

__device__ __forceinline__ float lrelu(float x) { return fmaxf(x, kSlope * x); }

// 3-instruction round-to-nearest-even f32->bf16 (prep kernel only).
__device__ __forceinline__ unsigned short bfrne(float a) {
    union { float f; unsigned u; } v; v.f = a;
    return (unsigned short)((v.u + 0x7FFFu + ((v.u >> 16) & 1u)) >> 16);
}

// packed 2x f32 -> 2x bf16 (RNE), single VALU op.
__device__ __forceinline__ unsigned cvtpk(float lo, float hi) {
    unsigned r;
    asm("v_cvt_pk_bf16_f32 %0, %1, %2" : "=v"(r) : "v"(lo), "v"(hi));
    return r;
}

// ---- pre-pass: pack W1/W2/W3 as bf16 MFMA B-frags into d_ws ----
// frag f: 0..3 = W1 (nt=f, K=16 zero-padded); 4..19 = W2 (nt=(f-4)>>2,
// ks=(f-4)&3); 20..35 = W3. Lane l of frag f lives at ws[f*512 + l*8 ..+7].
__global__ void prep_weights(const float* __restrict__ W1,
                             const float* __restrict__ W2,
                             const float* __restrict__ W3,
                             unsigned short* __restrict__ ws)
{
    int t = blockIdx.x * blockDim.x + threadIdx.x;
    if (t >= 36 * 64) return;
    int f = t >> 6, l = t & 63, c = l & 15, q = l >> 4;
    unsigned short v[8] = {0, 0, 0, 0, 0, 0, 0, 0};
    const float* src = nullptr; int row = 0, k0 = 0, K = 0;
    if (f < 4) {
        if (q < 2) { src = W1; row = 16 * f + c; k0 = q * 8; K = 16; }
    } else if (f < 20) {
        int g = f - 4;  src = W2; row = 16 * (g >> 2) + c; k0 = (g & 3) * 32 + q * 8; K = 128;
    } else {
        int g = f - 20; src = W3; row = 16 * (g >> 2) + c; k0 = (g & 3) * 32 + q * 8; K = 128;
    }
    if (src) {
        #pragma unroll
        for (int j = 0; j < 8; ++j) v[j] = bfrne(src[row * K + k0 + j]);
    }
    unsigned short* dst = ws + (size_t)f * 512 + l * 8;
    *(ushort4*)(dst)     = make_ushort4(v[0], v[1], v[2], v[3]);
    *(ushort4*)(dst + 4) = make_ushort4(v[4], v[5], v[6], v[7]);
}

__global__ __launch_bounds__(256, 3) void fused_mlp_v8(
    const float* __restrict__ X, const int* __restrict__ M,
    const unsigned short* __restrict__ WF,
    const float* __restrict__ B1, const float* __restrict__ B2,
    const float* __restrict__ B3, float* __restrict__ OUT)
{
    __shared__ __align__(16) short sX[4][2][32 * kXS];  // 36864 B
    __shared__ __align__(16) short sP[4][2][64];        //  1024 B

    const int t = threadIdx.x, w = t >> 6, l = t & 63, c = l & 15, q = l >> 4;
    const size_t bp0 = (size_t)blockIdx.x * 8 + w * 2;  // wave handles bp0, bp0+1

    // ---- masks for both bp ----
    unsigned mbits[2];
    bool anyv[2];
    #pragma unroll
    for (int u = 0; u < 2; ++u) {
        const int4* Mp = (const int4*)(M + (bp0 + u) * 32);
        const int4 mr0 = Mp[q], mr1 = Mp[4 + q];
        mbits[u] =
            (mr0.x ? 1u : 0u)  | (mr0.y ? 2u : 0u)  | (mr0.z ? 4u : 0u)  | (mr0.w ? 8u : 0u) |
            (mr1.x ? 16u : 0u) | (mr1.y ? 32u : 0u) | (mr1.z ? 64u : 0u) | (mr1.w ? 128u : 0u);
        anyv[u] = __any(mbits[u] != 0);
    }
    // Pool-mask addends: invalid row -> -inf => pool is max(pv, y+addm),
    // no per-element cmp/cndmask.
    float addm[2][8];
    #pragma unroll
    for (int u = 0; u < 2; ++u)
        #pragma unroll
        for (int i = 0; i < 8; ++i)
            addm[u][i] = ((mbits[u] >> i) & 1u) ? 0.f : -INFINITY;

    // ---- X loads for both bp: load + convert immediately ----
    bf16x8 a1f[2][2];
    #pragma unroll
    for (int u = 0; u < 2; ++u)
        #pragma unroll
        for (int mt = 0; mt < 2; ++mt) {
            union { bf16x8 v; unsigned uu[4]; } cv; cv.v = bf16x8{};
            if (q < 2) {
                const float4* p = (const float4*)(X + ((bp0 + u) * 32 + 16 * mt + c) * 16 + q * 8);
                float4 f0 = p[0], f1 = p[1];
                cv.uu[0] = cvtpk(f0.x, f0.y);
                cv.uu[1] = cvtpk(f0.z, f0.w);
                cv.uu[2] = cvtpk(f1.x, f1.y);
                cv.uu[3] = cvtpk(f1.z, f1.w);
            }
            a1f[u][mt] = cv.v;
        }

    f32x4 acc[2][2][4];   // [u][mt][nt]

    // ---- layer 1 (K=16 zero-padded to 32): one wf load feeds 4 MFMAs ----
    #pragma unroll
    for (int nt = 0; nt < 4; ++nt) {
        float b1 = B1[16 * nt + c];
        bf16x8 wf = *(const bf16x8*)(WF + (size_t)nt * 512 + l * 8);
        f32x4 c0 = { b1, b1, b1, b1 };
        #pragma unroll
        for (int u = 0; u < 2; ++u) {
            acc[u][0][nt] = __builtin_amdgcn_mfma_f32_16x16x32_bf16(a1f[u][0], wf, c0, 0, 0, 0);
            acc[u][1][nt] = __builtin_amdgcn_mfma_f32_16x16x32_bf16(a1f[u][1], wf, c0, 0, 0, 0);
        }
    }

    // ---- epilogue for one bp: unmasked lrelu -> LDS bf16, masked pool ----
    auto epilogue = [&](int u, short* xb_, short* pl_) {
        float pool[4];
        #pragma unroll
        for (int nt = 0; nt < 4; ++nt) {
            float pv = -INFINITY;
            #pragma unroll
            for (int mt = 0; mt < 2; ++mt) {
                short* base = &xb_[(16 * mt + 4 * q) * kXS + 16 * nt + c];
                float y0 = lrelu(acc[u][mt][nt][0]);
                float y1 = lrelu(acc[u][mt][nt][1]);
                float y2 = lrelu(acc[u][mt][nt][2]);
                float y3 = lrelu(acc[u][mt][nt][3]);
                pv = fmaxf(pv, y0 + addm[u][mt * 4 + 0]);
                pv = fmaxf(pv, y1 + addm[u][mt * 4 + 1]);
                pv = fmaxf(pv, y2 + addm[u][mt * 4 + 2]);
                pv = fmaxf(pv, y3 + addm[u][mt * 4 + 3]);
                unsigned u01 = cvtpk(y0, y1);
                unsigned u23 = cvtpk(y2, y3);
                base[0 * kXS] = (short)u01;
                base[1 * kXS] = (short)(u01 >> 16);
                base[2 * kXS] = (short)u23;
                base[3 * kXS] = (short)(u23 >> 16);
            }
            pv = fmaxf(pv, __shfl_xor(pv, 16));
            pv = fmaxf(pv, __shfl_xor(pv, 32));
            pool[nt] = anyv[u] ? pv : 0.f;
        }
        float ps = (q & 2) ? ((q & 1) ? pool[3] : pool[2])
                           : ((q & 1) ? pool[1] : pool[0]);
        pl_[16 * q + c] = (short)cvtpk(ps, ps);
    };

    // ---- K=128 layer for BOTH bp: one wf load feeds 4 MFMAs ----
    auto layerK = [&](int fb, const float* Bp) {
        #pragma unroll
        for (int nt = 0; nt < 4; ++nt) {
            float bb = Bp[16 * nt + c];
            #pragma unroll
            for (int u = 0; u < 2; ++u) {
                acc[u][0][nt] = f32x4{ bb, bb, bb, bb };
                acc[u][1][nt] = acc[u][0][nt];
            }
        }
        #pragma unroll
        for (int ks = 0; ks < 4; ++ks) {
            bf16x8 am[2][2];
            #pragma unroll
            for (int u = 0; u < 2; ++u) {
                const short* xb_ = &sX[w][u][0];
                const short* pl_ = &sP[w][u][0];
                if (ks < 2) {
                    am[u][0] = *(const bf16x8*)&xb_[(     c) * kXS + ks * 32 + q * 8];
                    am[u][1] = *(const bf16x8*)&xb_[(16 + c) * kXS + ks * 32 + q * 8];
                } else {
                    am[u][0] = *(const bf16x8*)&pl_[(ks - 2) * 32 + q * 8];  // quad-bcast
                    am[u][1] = am[u][0];
                }
            }
            #pragma unroll
            for (int nt = 0; nt < 4; ++nt) {
                bf16x8 wf = *(const bf16x8*)(WF + ((size_t)(fb + nt * 4 + ks)) * 512 + l * 8);
                #pragma unroll
                for (int u = 0; u < 2; ++u) {
                    acc[u][0][nt] = __builtin_amdgcn_mfma_f32_16x16x32_bf16(am[u][0], wf, acc[u][0][nt], 0, 0, 0);
                    acc[u][1][nt] = __builtin_amdgcn_mfma_f32_16x16x32_bf16(am[u][1], wf, acc[u][1][nt], 0, 0, 0);
                }
            }
        }
    };

    epilogue(0, &sX[w][0][0], &sP[w][0][0]);
    epilogue(1, &sX[w][1][0], &sP[w][1][0]);
    layerK(4, B2);

    epilogue(0, &sX[w][0][0], &sP[w][0][0]);
    epilogue(1, &sX[w][1][0], &sP[w][1][0]);
    layerK(20, B3);

    // ---- layer-3 pool == final output, per bp ----
    #pragma unroll
    for (int u = 0; u < 2; ++u) {
        float pool[4];
        #pragma unroll
        for (int nt = 0; nt < 4; ++nt) {
            float pv = -INFINITY;
            #pragma unroll
            for (int mt = 0; mt < 2; ++mt)
                #pragma unroll
                for (int r = 0; r < 4; ++r)
                    pv = fmaxf(pv, lrelu(acc[u][mt][nt][r]) + addm[u][mt * 4 + r]);
            pv = fmaxf(pv, __shfl_xor(pv, 16));
            pv = fmaxf(pv, __shfl_xor(pv, 32));
            pool[nt] = anyv[u] ? pv : 0.f;
        }
        float ps = (q & 2) ? ((q & 1) ? pool[3] : pool[2])
                           : ((q & 1) ? pool[1] : pool[0]);
        OUT[(bp0 + u) * 64 + 16 * q + c] = ps;
    }
}
} // namespace

extern "C" void kernel_launch(void* const* d_in, const int* in_sizes, int n_in,
                              void* d_out, int out_size, void* d_ws, size_t ws_size,
                              hipStream_t stream) {
    (void)in_sizes; (void)n_in; (void)ws_size; (void)out_size;
    const float* X  = (const float*)d_in[0];
    const int*   M  = (const int*)d_in[1];
    const float* W1 = (const float*)d_in[2];
    const float* B1 = (const float*)d_in[3];
    const float* W2 = (const float*)d_in[4];
    const float* B2 = (const float*)d_in[5];
    const float* W3 = (const float*)d_in[6];
    const float* B3 = (const float*)d_in[7];
    float* OUT = (float*)d_out;
    unsigned short* WF = (unsigned short*)d_ws;   // needs 36 KB of scratch

    prep_weights<<<(36 * 64 + 255) / 256, 256, 0, stream>>>(W1, W2, W3, WF);
    // 2048 blocks x 4 waves x 2 bp = 16384 bp; two bp per wave
    fused_mlp_v8<<<2048, 256, 0, stream>>>(X, M, WF, B1, B2, B3, OUT);
}